// Round 1
// baseline (563.732 us; speedup 1.0000x reference)
//
#include <hip/hip_runtime.h>
#include <hip/hip_bf16.h>

#define BS 16384    // B*S tokens
#define HDIM 4096   // hidden dim
#define NE 64       // experts
#define KC 64       // K-chunk per LDS stage
#define TT 32       // tokens per block (K1)
#define CAP 512     // max boundary candidates per expert
#define DELTA 2e-3f // bf16-split GEMM error margin (actual err ~2e-5 rms)
#define K3B 1024    // k3 grid (16 tokens/block, 4 blocks/CU)

typedef __bf16 bf16x8 __attribute__((ext_vector_type(8)));
typedef float f32x4 __attribute__((ext_vector_type(4)));
union Frag { uint4 q; bf16x8 v; };

__device__ inline unsigned f2key(float f) {
    unsigned u = __float_as_uint(f);
    return (u & 0x80000000u) ? ~u : (u | 0x80000000u);
}
__device__ inline float key2f(unsigned k) {
    unsigned u = (k & 0x80000000u) ? (k ^ 0x80000000u) : ~k;
    return __uint_as_float(u);
}
__device__ inline unsigned pack_hi(float a, float b) {  // bf16(a)|bf16(b)<<16 (trunc)
    return (__float_as_uint(a) >> 16) | (__float_as_uint(b) & 0xFFFF0000u);
}
__device__ inline float bf16_resid(float a) {  // a - trunc_bf16(a), exact
    return a - __uint_as_float(__float_as_uint(a) & 0xFFFF0000u);
}

// ---------------------------------------------------------------------------
// K0: convert W -> bf16 hi/lo; zero token-major winner bitmap + k3 counter.
// ---------------------------------------------------------------------------
__global__ __launch_bounds__(256) void k0_init(const float* __restrict__ W,
                                               unsigned short* __restrict__ Wh,
                                               unsigned short* __restrict__ Wl,
                                               unsigned long long* __restrict__ win_t,
                                               unsigned* __restrict__ counter) {
    const int gtid = blockIdx.x * 256 + threadIdx.x;  // 0..65535
    const size_t f = (size_t)gtid * 4;                // covers NE*HDIM = 262144
    float4 w = *(const float4*)(W + f);
    uint2 hh, ll;
    hh.x = pack_hi(w.x, w.y); hh.y = pack_hi(w.z, w.w);
    ll.x = pack_hi(bf16_resid(w.x), bf16_resid(w.y));
    ll.y = pack_hi(bf16_resid(w.z), bf16_resid(w.w));
    *(uint2*)(Wh + f) = hh;
    *(uint2*)(Wl + f) = ll;
    if (gtid < BS) win_t[gtid] = 0ull;
    if (gtid == 0) *counter = 0u;
}

// ---------------------------------------------------------------------------
// K1: logits = A @ W^T via bf16-split MFMA (AhBh+AlBh+AhBl, 16x16x32).
// 32 tok x 64 exp tile, 256 thr (4 waves: 2 M-tiles x 2 N-halves), grid 512
// -> 2 blocks/CU (LDS 2x55296 B = 110.6 KB) for cross-block barrier overlap.
// Double-buffered LDS, one __syncthreads/chunk, register prefetch.
// Epilogue: Lg token-major + KeyT expert-major via LDS transpose.
// (UNCHANGED from proven version — HBM-bound at ~50 µs.)
// ---------------------------------------------------------------------------
__global__ __launch_bounds__(256, 2) void k1_gemm(const float* __restrict__ A,
                                                  const unsigned short* __restrict__ Wh,
                                                  const unsigned short* __restrict__ Wl,
                                                  float* __restrict__ Lg,
                                                  unsigned* __restrict__ KeyT) {
    // per buffer (13824 shorts): As_h[32][72] @0, As_l @2304, Ws_h[64][72] @4608,
    // Ws_l @9216. Two buffers = 27648 shorts = 55296 B.
    __shared__ __align__(16) unsigned short sbuf[2 * 13824];

    const int tid = threadIdx.x;
    const int T0 = blockIdx.x * TT;

    const int arow = tid >> 3, aseg = tid & 7;  // A staging: row 0..31, 8-float seg

    const int lane = tid & 63, w = tid >> 6;
    const int m = lane & 15, q = lane >> 4;
    const int wm = w & 1;   // M tile (16 tokens)
    const int wn = w >> 1;  // N half (32 experts)

    const float* Aprow = A + (size_t)(T0 + arow) * HDIM + aseg * 8;

    f32x4 acc[2] = {{0.f, 0.f, 0.f, 0.f}, {0.f, 0.f, 0.f, 0.f}};

    float4 pa0 = *(const float4*)(Aprow);
    float4 pa1 = *(const float4*)(Aprow + 4);
    uint4 pwh[2], pwl[2];
#pragma unroll
    for (int i = 0; i < 2; ++i) {
        const int u = i * 256 + tid;               // 0..511
        const int r = u >> 3, blk = u & 7;         // row 0..63, 8-short seg
        pwh[i] = *(const uint4*)(Wh + (size_t)r * HDIM + blk * 8);
        pwl[i] = *(const uint4*)(Wl + (size_t)r * HDIM + blk * 8);
    }

    // stage chunk 0 into buffer 0
    {
        unsigned short* B = sbuf;
        uint4 H, L;
        H.x = pack_hi(pa0.x, pa0.y); H.y = pack_hi(pa0.z, pa0.w);
        H.z = pack_hi(pa1.x, pa1.y); H.w = pack_hi(pa1.z, pa1.w);
        L.x = pack_hi(bf16_resid(pa0.x), bf16_resid(pa0.y));
        L.y = pack_hi(bf16_resid(pa0.z), bf16_resid(pa0.w));
        L.z = pack_hi(bf16_resid(pa1.x), bf16_resid(pa1.y));
        L.w = pack_hi(bf16_resid(pa1.z), bf16_resid(pa1.w));
        *(uint4*)(B + arow * 72 + aseg * 8) = H;
        *(uint4*)(B + 2304 + arow * 72 + aseg * 8) = L;
#pragma unroll
        for (int i = 0; i < 2; ++i) {
            const int u = i * 256 + tid;
            const int r = u >> 3, blk = u & 7;
            *(uint4*)(B + 4608 + r * 72 + blk * 8) = pwh[i];
            *(uint4*)(B + 9216 + r * 72 + blk * 8) = pwl[i];
        }
    }

    for (int c = 0; c < HDIM / KC; ++c) {
        if (c + 1 < HDIM / KC) {  // issue prefetch for chunk c+1
            const int c0 = (c + 1) * KC;
            pa0 = *(const float4*)(Aprow + c0);
            pa1 = *(const float4*)(Aprow + c0 + 4);
#pragma unroll
            for (int i = 0; i < 2; ++i) {
                const int u = i * 256 + tid;
                const int r = u >> 3, blk = u & 7;
                pwh[i] = *(const uint4*)(Wh + (size_t)r * HDIM + c0 + blk * 8);
                pwl[i] = *(const uint4*)(Wl + (size_t)r * HDIM + c0 + blk * 8);
            }
        }
        __syncthreads();  // buf[c&1] visible; prior reads of buf[(c+1)&1] done
        {
            const unsigned short* B = sbuf + (c & 1) * 13824;
            const unsigned short* Ash = B + (wm * 16 + m) * 72;
            const unsigned short* Asl = Ash + 2304;
#pragma unroll
            for (int kh = 0; kh < 2; ++kh) {
                const int ko = kh * 32 + q * 8;
                Frag ah, al;
                ah.q = *(const uint4*)(Ash + ko);
                al.q = *(const uint4*)(Asl + ko);
#pragma unroll
                for (int nt = 0; nt < 2; ++nt) {
                    const int er = wn * 32 + nt * 16 + m;
                    Frag bh, bl;
                    bh.q = *(const uint4*)(B + 4608 + er * 72 + ko);
                    bl.q = *(const uint4*)(B + 9216 + er * 72 + ko);
                    acc[nt] = __builtin_amdgcn_mfma_f32_16x16x32_bf16(ah.v, bh.v, acc[nt], 0, 0, 0);
                    acc[nt] = __builtin_amdgcn_mfma_f32_16x16x32_bf16(al.v, bh.v, acc[nt], 0, 0, 0);
                    acc[nt] = __builtin_amdgcn_mfma_f32_16x16x32_bf16(ah.v, bl.v, acc[nt], 0, 0, 0);
                }
            }
        }
        if (c + 1 < HDIM / KC) {  // stage chunk c+1 into the other buffer
            unsigned short* B = sbuf + ((c + 1) & 1) * 13824;
            uint4 H, L;
            H.x = pack_hi(pa0.x, pa0.y); H.y = pack_hi(pa0.z, pa0.w);
            H.z = pack_hi(pa1.x, pa1.y); H.w = pack_hi(pa1.z, pa1.w);
            L.x = pack_hi(bf16_resid(pa0.x), bf16_resid(pa0.y));
            L.y = pack_hi(bf16_resid(pa0.z), bf16_resid(pa0.w));
            L.z = pack_hi(bf16_resid(pa1.x), bf16_resid(pa1.y));
            L.w = pack_hi(bf16_resid(pa1.z), bf16_resid(pa1.w));
            *(uint4*)(B + arow * 72 + aseg * 8) = H;
            *(uint4*)(B + 2304 + arow * 72 + aseg * 8) = L;
#pragma unroll
            for (int i = 0; i < 2; ++i) {
                const int u = i * 256 + tid;
                const int r = u >> 3, blk = u & 7;
                *(uint4*)(B + 4608 + r * 72 + blk * 8) = pwh[i];
                *(uint4*)(B + 9216 + r * 72 + blk * 8) = pwl[i];
            }
        }
    }

    // Epilogue: Lg direct, KeyT via LDS transpose (coalesced per expert)
    __syncthreads();
    float* Sc = (float*)sbuf;  // [32][68] floats = 8704 B
#pragma unroll
    for (int nt = 0; nt < 2; ++nt) {
        const int e = wn * 32 + nt * 16 + m;  // C/D: col = lane&15
#pragma unroll
        for (int r = 0; r < 4; ++r) {
            const int tl = wm * 16 + q * 4 + r;  // C/D: row = quad*4+reg
            const float v = acc[nt][r];
            Sc[tl * 68 + e] = v;
            Lg[(size_t)(T0 + tl) * NE + e] = v;
        }
    }
    __syncthreads();
    {
        const int e = tid >> 2, jj = tid & 3;  // 8 tokens per thread
        unsigned kk[8];
#pragma unroll
        for (int r = 0; r < 8; ++r) kk[r] = f2key(Sc[(jj * 8 + r) * 68 + e]);
        uint4 v0 = {kk[0], kk[1], kk[2], kk[3]}, v1 = {kk[4], kk[5], kk[6], kk[7]};
        unsigned* dst = KeyT + (size_t)e * BS + T0 + jj * 8;
        *(uint4*)dst = v0;
        *(uint4*)(dst + 4) = v1;
    }
}

// ---------------------------------------------------------------------------
// K2 (fused select+resolve): per-expert C-th-largest key bracket via short
// binary search (keys in 16 VGPRs/thread). Fast path: logits' threshold is
// provably in [2.0, 4.0) for this distribution -> key prefix 0xC0xxxxxx;
// verified at runtime by two bracket counts (full 17-step search fallback).
// Search stops at bit 15 (bracket width ~0.008); candidate window widened by
// the bracket -> ~11 candidates avg (CAP=512 margin ~50x). Then same block:
// exact fp64 dots for candidates (16 waves), serial top-'needed' pick,
// win_t bits. One barrier per count-round (per-step LDS atomic slots).
// ---------------------------------------------------------------------------
__global__ __launch_bounds__(1024) void k2_fused(const unsigned* __restrict__ KeyT,
                                                 const int* __restrict__ Cptr,
                                                 const float* __restrict__ A,
                                                 const float* __restrict__ W,
                                                 unsigned* __restrict__ khi_g,
                                                 unsigned long long* __restrict__ win_t) {
    const int e = blockIdx.x, tid = threadIdx.x;
    const int wid = tid >> 6, lane = tid & 63;
    const int C = *Cptr;
    const unsigned* col = KeyT + (size_t)e * BS;

    unsigned key[16];
#pragma unroll
    for (int j4 = 0; j4 < 4; ++j4) {
        const uint4 v = *(const uint4*)(col + j4 * 4096 + tid * 4);
        key[j4 * 4 + 0] = v.x; key[j4 * 4 + 1] = v.y;
        key[j4 * 4 + 2] = v.z; key[j4 * 4 + 3] = v.w;
    }
    // token index of key[j] = (j>>2)*4096 + tid*4 + (j&3)

    __shared__ int s_arr[20];   // one slot per count-round (max 2+17+1)
    __shared__ int s_nc;
    __shared__ int sidx[CAP];
    __shared__ double sval[CAP];
    if (tid < 20) s_arr[tid] = 0;
    if (tid == 0) s_nc = 0;
    __syncthreads();

    int step = 0;
    auto bcount = [&](unsigned T) -> int {  // count(key >= T) over all 16384
        int c = 0;
#pragma unroll
        for (int j = 0; j < 16; ++j) c += (key[j] >= T);
#pragma unroll
        for (int off = 32; off; off >>= 1) c += __shfl_xor(c, off);
        if (lane == 0) atomicAdd(&s_arr[step], c);
        __syncthreads();
        return s_arr[step++];
    };

    const int cLo = bcount(0xC0000000u);  // count(logit >= 2.0)
    const int cHi = bcount(0xC0800000u);  // count(logit >= 4.0)
    unsigned K; int bstart;
    if (cLo >= C && cHi < C) { K = 0xC0000000u; bstart = 22; }  // fast path
    else                     { K = 0u;          bstart = 31; }  // safe fallback
    for (int b = bstart; b >= 15; --b) {
        const unsigned T = K | (1u << b);
        if (bcount(T) >= C) K = T;
    }
    // C-th key in [K, K+0x8000): bracket the threshold, widen by DELTA.
    const float vlo = key2f(K);
    const float vhi = key2f(K + 0x8000u);
    const unsigned khi = f2key(vhi + DELTA);
    const unsigned klo = f2key(vlo - DELTA);
    const int nd = bcount(khi + 1u);  // definite ins: key > khi
    int need = C - nd;

#pragma unroll
    for (int j = 0; j < 16; ++j) {
        if (key[j] >= klo && key[j] <= khi) {
            const int pos = atomicAdd(&s_nc, 1);
            if (pos < CAP) sidx[pos] = (j >> 2) * 4096 + tid * 4 + (j & 3);
        }
    }
    __syncthreads();
    int n = s_nc; if (n > CAP) n = CAP;
    if (need > n) need = n; if (need < 0) need = 0;

    // exact fp64 dots for candidates, one wave each (16 waves)
    const float* Wr = W + (size_t)e * HDIM;
    for (int c = wid; c < n; c += 16) {
        const int t = sidx[c];
        const float* Ar = A + (size_t)t * HDIM;
        double ps = 0.0;
#pragma unroll 8
        for (int j = 0; j < HDIM / 64; ++j)
            ps += (double)Ar[j * 64 + lane] * (double)Wr[j * 64 + lane];
#pragma unroll
        for (int off = 32; off; off >>= 1) ps += __shfl_xor(ps, off);
        if (lane == 0) sval[c] = ps;
    }
    __syncthreads();
    if (tid == 0) {
        khi_g[e] = khi;
        for (int s = 0; s < need; ++s) {  // top-'need' by (fp64 desc, idx asc)
            int best = -1;
            for (int c = 0; c < n; ++c) {
                if (sidx[c] < 0) continue;
                if (best < 0 || sval[c] > sval[best] ||
                    (sval[c] == sval[best] && sidx[c] < sidx[best]))
                    best = c;
            }
            atomicOr(&win_t[sidx[best]], 1ull << e);
            sidx[best] = -1;
        }
    }
}

// ---------------------------------------------------------------------------
// K3 (fused softmax + aux): per-token softmax+mask+renorm, per-block fp64
// importance partials, then last-block (threadfence + device-scope counter)
// reduces partials and writes aux. 1024 blocks (16 tok each) = 4 blocks/CU.
// ---------------------------------------------------------------------------
__global__ __launch_bounds__(256) void k3_softmax(const float* __restrict__ Lg,
                                                  const unsigned* __restrict__ khi_g,
                                                  const unsigned long long* __restrict__ win_t,
                                                  float* __restrict__ probs,
                                                  float* __restrict__ out_map,
                                                  double* __restrict__ imp_partial,
                                                  unsigned* __restrict__ counter,
                                                  float* __restrict__ out_aux) {
    const int tid = threadIdx.x, w = tid >> 6, e = tid & 63, b = blockIdx.x;
    __shared__ unsigned skhi[64];
    __shared__ double sim[4][64];
    __shared__ int s_last;
    if (tid < 64) skhi[tid] = khi_g[tid];
    __syncthreads();
    const unsigned kh = skhi[e];
    double accim = 0.0;
#pragma unroll
    for (int it = 0; it < 4; ++it) {
        const int t = b * 16 + it * 4 + w;
        const float x = Lg[(size_t)t * NE + e];
        const unsigned key = f2key(x);
        float mfl;
        if (key > kh) mfl = 1.f;
        else mfl = (float)((win_t[t] >> e) & 1ull);
        const float ev = expf(x);
        const float evm = ev * mfl;
        float s1 = ev, s2 = evm;
#pragma unroll
        for (int off = 32; off; off >>= 1) {
            s1 += __shfl_xor(s1, off);
            s2 += __shfl_xor(s2, off);
        }
        const float o = evm / (s2 + 1e-6f * s1);  // == (p*m)/(sum(p*m)+eps)
        probs[(size_t)t * NE + e] = o;
        out_map[(size_t)t * NE + e] = mfl;
        accim += (double)o;
    }
    sim[w][e] = accim;
    __syncthreads();
    if (w == 0)
        imp_partial[(size_t)b * NE + e] = sim[0][e] + sim[1][e] + sim[2][e] + sim[3][e];
    __threadfence();   // make partials visible device-wide before signaling
    __syncthreads();
    if (tid == 0) s_last = (atomicAdd(counter, 1u) == gridDim.x - 1);
    __syncthreads();
    if (!s_last) return;
    __threadfence();   // acquire: other blocks' partials now visible

    // last block: reduce all partials, aux = (std(imp,ddof=1)/(mean+eps))^2
    double v = 0.0;
    for (int bb = w; bb < (int)gridDim.x; bb += 4)
        v += imp_partial[(size_t)bb * NE + e];
    sim[w][e] = v;
    __syncthreads();
    if (w == 0) {
        const double ve = sim[0][e] + sim[1][e] + sim[2][e] + sim[3][e];
        double s = ve;
#pragma unroll
        for (int off = 32; off; off >>= 1) s += __shfl_xor(s, off);
        const double mean = s / 64.0;
        const double d = ve - mean;
        double ss = d * d;
#pragma unroll
        for (int off = 32; off; off >>= 1) ss += __shfl_xor(ss, off);
        if (e == 0) {
            const double var = ss / 63.0;   // ddof=1
            const double dn = mean + 1e-6;
            out_aux[0] = (float)(var / (dn * dn));  // load_loss == 0 (load == C)
        }
    }
}

extern "C" void kernel_launch(void* const* d_in, const int* in_sizes, int n_in,
                              void* d_out, int out_size, void* d_ws, size_t ws_size,
                              hipStream_t stream) {
    const float* A = (const float*)d_in[0];
    const float* W = (const float*)d_in[1];
    const int* Cptr = (const int*)d_in[2];

    float* out_probs = (float*)d_out;
    float* out_map = out_probs + (size_t)BS * NE;
    float* out_aux = out_map + (size_t)BS * NE;

    char* wsb = (char*)d_ws;
    float*              Lg     = (float*)wsb;                                    // 4 MB
    unsigned*           KeyT   = (unsigned*)(wsb + (4ull << 20));                // 4 MB
    unsigned short*     Wh     = (unsigned short*)(wsb + (8ull << 20));          // 512 KB
    unsigned short*     Wl     = (unsigned short*)(wsb + (8ull << 20) + (512ull << 10));
    unsigned long long* win_t  = (unsigned long long*)(wsb + (9ull << 20));      // 128 KB
    unsigned*           khi_g  = (unsigned*)(wsb + (9ull << 20) + (128ull << 10));
    unsigned*           counter= (unsigned*)(wsb + (9ull << 20) + (132ull << 10));
    double*             imp_p  = (double*)(wsb + (9ull << 20) + (256ull << 10)); // 512 KB

    k0_init<<<256, 256, 0, stream>>>(W, Wh, Wl, win_t, counter);
    k1_gemm<<<BS / TT, 256, 0, stream>>>(A, Wh, Wl, Lg, KeyT);
    k2_fused<<<NE, 1024, 0, stream>>>(KeyT, Cptr, A, W, khi_g, win_t);
    k3_softmax<<<K3B, 256, 0, stream>>>(Lg, khi_g, win_t, out_probs, out_map, imp_p,
                                        counter, out_aux);
}

// Round 2
// 469.028 us; speedup vs baseline: 1.2019x; 1.2019x over previous
//
#include <hip/hip_runtime.h>
#include <hip/hip_bf16.h>

#define BS 16384    // B*S tokens
#define HDIM 4096   // hidden dim
#define NE 64       // experts
#define KC 64       // K-chunk per LDS stage
#define TT 32       // tokens per block (K1)
#define CAP 512     // max boundary candidates per expert
#define DELTA 2e-3f // bf16-split GEMM error margin (actual err ~2e-5 rms)

typedef __bf16 bf16x8 __attribute__((ext_vector_type(8)));
typedef float f32x4 __attribute__((ext_vector_type(4)));
union Frag { uint4 q; bf16x8 v; };

__device__ inline unsigned f2key(float f) {
    unsigned u = __float_as_uint(f);
    return (u & 0x80000000u) ? ~u : (u | 0x80000000u);
}
__device__ inline float key2f(unsigned k) {
    unsigned u = (k & 0x80000000u) ? (k ^ 0x80000000u) : ~k;
    return __uint_as_float(u);
}
__device__ inline unsigned pack_hi(float a, float b) {  // bf16(a)|bf16(b)<<16 (trunc)
    return (__float_as_uint(a) >> 16) | (__float_as_uint(b) & 0xFFFF0000u);
}
__device__ inline float bf16_resid(float a) {  // a - trunc_bf16(a), exact
    return a - __uint_as_float(__float_as_uint(a) & 0xFFFF0000u);
}

// ---------------------------------------------------------------------------
// K0: convert W -> bf16 hi/lo; zero token-major winner bitmap.
// ---------------------------------------------------------------------------
__global__ __launch_bounds__(256) void k0_init(const float* __restrict__ W,
                                               unsigned short* __restrict__ Wh,
                                               unsigned short* __restrict__ Wl,
                                               unsigned long long* __restrict__ win_t) {
    const int gtid = blockIdx.x * 256 + threadIdx.x;  // 0..65535
    const size_t f = (size_t)gtid * 4;                // covers NE*HDIM = 262144
    float4 w = *(const float4*)(W + f);
    uint2 hh, ll;
    hh.x = pack_hi(w.x, w.y); hh.y = pack_hi(w.z, w.w);
    ll.x = pack_hi(bf16_resid(w.x), bf16_resid(w.y));
    ll.y = pack_hi(bf16_resid(w.z), bf16_resid(w.w));
    *(uint2*)(Wh + f) = hh;
    *(uint2*)(Wl + f) = ll;
    if (gtid < BS) win_t[gtid] = 0ull;
}

// ---------------------------------------------------------------------------
// K1: logits = A @ W^T via bf16-split MFMA (AhBh+AlBh+AhBl, 16x16x32).
// 32 tok x 64 exp tile, 256 thr (4 waves: 2 M-tiles x 2 N-halves), grid 512
// -> 2 blocks/CU (LDS 2x55296 B = 110.6 KB) for cross-block barrier overlap.
// Double-buffered LDS, one __syncthreads/chunk, register prefetch.
// Epilogue: Lg token-major + KeyT expert-major via LDS transpose.
// (UNCHANGED — HBM-bound at ~50 µs.)
// ---------------------------------------------------------------------------
__global__ __launch_bounds__(256, 2) void k1_gemm(const float* __restrict__ A,
                                                  const unsigned short* __restrict__ Wh,
                                                  const unsigned short* __restrict__ Wl,
                                                  float* __restrict__ Lg,
                                                  unsigned* __restrict__ KeyT) {
    // per buffer (13824 shorts): As_h[32][72] @0, As_l @2304, Ws_h[64][72] @4608,
    // Ws_l @9216. Two buffers = 27648 shorts = 55296 B.
    __shared__ __align__(16) unsigned short sbuf[2 * 13824];

    const int tid = threadIdx.x;
    const int T0 = blockIdx.x * TT;

    const int arow = tid >> 3, aseg = tid & 7;  // A staging: row 0..31, 8-float seg

    const int lane = tid & 63, w = tid >> 6;
    const int m = lane & 15, q = lane >> 4;
    const int wm = w & 1;   // M tile (16 tokens)
    const int wn = w >> 1;  // N half (32 experts)

    const float* Aprow = A + (size_t)(T0 + arow) * HDIM + aseg * 8;

    f32x4 acc[2] = {{0.f, 0.f, 0.f, 0.f}, {0.f, 0.f, 0.f, 0.f}};

    float4 pa0 = *(const float4*)(Aprow);
    float4 pa1 = *(const float4*)(Aprow + 4);
    uint4 pwh[2], pwl[2];
#pragma unroll
    for (int i = 0; i < 2; ++i) {
        const int u = i * 256 + tid;               // 0..511
        const int r = u >> 3, blk = u & 7;         // row 0..63, 8-short seg
        pwh[i] = *(const uint4*)(Wh + (size_t)r * HDIM + blk * 8);
        pwl[i] = *(const uint4*)(Wl + (size_t)r * HDIM + blk * 8);
    }

    // stage chunk 0 into buffer 0
    {
        unsigned short* B = sbuf;
        uint4 H, L;
        H.x = pack_hi(pa0.x, pa0.y); H.y = pack_hi(pa0.z, pa0.w);
        H.z = pack_hi(pa1.x, pa1.y); H.w = pack_hi(pa1.z, pa1.w);
        L.x = pack_hi(bf16_resid(pa0.x), bf16_resid(pa0.y));
        L.y = pack_hi(bf16_resid(pa0.z), bf16_resid(pa0.w));
        L.z = pack_hi(bf16_resid(pa1.x), bf16_resid(pa1.y));
        L.w = pack_hi(bf16_resid(pa1.z), bf16_resid(pa1.w));
        *(uint4*)(B + arow * 72 + aseg * 8) = H;
        *(uint4*)(B + 2304 + arow * 72 + aseg * 8) = L;
#pragma unroll
        for (int i = 0; i < 2; ++i) {
            const int u = i * 256 + tid;
            const int r = u >> 3, blk = u & 7;
            *(uint4*)(B + 4608 + r * 72 + blk * 8) = pwh[i];
            *(uint4*)(B + 9216 + r * 72 + blk * 8) = pwl[i];
        }
    }

    for (int c = 0; c < HDIM / KC; ++c) {
        if (c + 1 < HDIM / KC) {  // issue prefetch for chunk c+1
            const int c0 = (c + 1) * KC;
            pa0 = *(const float4*)(Aprow + c0);
            pa1 = *(const float4*)(Aprow + c0 + 4);
#pragma unroll
            for (int i = 0; i < 2; ++i) {
                const int u = i * 256 + tid;
                const int r = u >> 3, blk = u & 7;
                pwh[i] = *(const uint4*)(Wh + (size_t)r * HDIM + c0 + blk * 8);
                pwl[i] = *(const uint4*)(Wl + (size_t)r * HDIM + c0 + blk * 8);
            }
        }
        __syncthreads();  // buf[c&1] visible; prior reads of buf[(c+1)&1] done
        {
            const unsigned short* B = sbuf + (c & 1) * 13824;
            const unsigned short* Ash = B + (wm * 16 + m) * 72;
            const unsigned short* Asl = Ash + 2304;
#pragma unroll
            for (int kh = 0; kh < 2; ++kh) {
                const int ko = kh * 32 + q * 8;
                Frag ah, al;
                ah.q = *(const uint4*)(Ash + ko);
                al.q = *(const uint4*)(Asl + ko);
#pragma unroll
                for (int nt = 0; nt < 2; ++nt) {
                    const int er = wn * 32 + nt * 16 + m;
                    Frag bh, bl;
                    bh.q = *(const uint4*)(B + 4608 + er * 72 + ko);
                    bl.q = *(const uint4*)(B + 9216 + er * 72 + ko);
                    acc[nt] = __builtin_amdgcn_mfma_f32_16x16x32_bf16(ah.v, bh.v, acc[nt], 0, 0, 0);
                    acc[nt] = __builtin_amdgcn_mfma_f32_16x16x32_bf16(al.v, bh.v, acc[nt], 0, 0, 0);
                    acc[nt] = __builtin_amdgcn_mfma_f32_16x16x32_bf16(ah.v, bl.v, acc[nt], 0, 0, 0);
                }
            }
        }
        if (c + 1 < HDIM / KC) {  // stage chunk c+1 into the other buffer
            unsigned short* B = sbuf + ((c + 1) & 1) * 13824;
            uint4 H, L;
            H.x = pack_hi(pa0.x, pa0.y); H.y = pack_hi(pa0.z, pa0.w);
            H.z = pack_hi(pa1.x, pa1.y); H.w = pack_hi(pa1.z, pa1.w);
            L.x = pack_hi(bf16_resid(pa0.x), bf16_resid(pa0.y));
            L.y = pack_hi(bf16_resid(pa0.z), bf16_resid(pa0.w));
            L.z = pack_hi(bf16_resid(pa1.x), bf16_resid(pa1.y));
            L.w = pack_hi(bf16_resid(pa1.z), bf16_resid(pa1.w));
            *(uint4*)(B + arow * 72 + aseg * 8) = H;
            *(uint4*)(B + 2304 + arow * 72 + aseg * 8) = L;
#pragma unroll
            for (int i = 0; i < 2; ++i) {
                const int u = i * 256 + tid;
                const int r = u >> 3, blk = u & 7;
                *(uint4*)(B + 4608 + r * 72 + blk * 8) = pwh[i];
                *(uint4*)(B + 9216 + r * 72 + blk * 8) = pwl[i];
            }
        }
    }

    // Epilogue: Lg direct, KeyT via LDS transpose (coalesced per expert)
    __syncthreads();
    float* Sc = (float*)sbuf;  // [32][68] floats = 8704 B
#pragma unroll
    for (int nt = 0; nt < 2; ++nt) {
        const int e = wn * 32 + nt * 16 + m;  // C/D: col = lane&15
#pragma unroll
        for (int r = 0; r < 4; ++r) {
            const int tl = wm * 16 + q * 4 + r;  // C/D: row = quad*4+reg
            const float v = acc[nt][r];
            Sc[tl * 68 + e] = v;
            Lg[(size_t)(T0 + tl) * NE + e] = v;
        }
    }
    __syncthreads();
    {
        const int e = tid >> 2, jj = tid & 3;  // 8 tokens per thread
        unsigned kk[8];
#pragma unroll
        for (int r = 0; r < 8; ++r) kk[r] = f2key(Sc[(jj * 8 + r) * 68 + e]);
        uint4 v0 = {kk[0], kk[1], kk[2], kk[3]}, v1 = {kk[4], kk[5], kk[6], kk[7]};
        unsigned* dst = KeyT + (size_t)e * BS + T0 + jj * 8;
        *(uint4*)dst = v0;
        *(uint4*)(dst + 4) = v1;
    }
}

// ---------------------------------------------------------------------------
// K2 (fused select+resolve): per-expert C-th-largest key bracket via short
// binary search (keys in 16 VGPRs/thread). Fast path: threshold in [2.0,4.0)
// -> key prefix 0xC0xxxxxx; verified at runtime by two bracket counts (full
// search fallback). Search stops at bit 15 (bracket ~0.008); candidates
// (~11 avg, CAP margin ~50x) resolved by exact fp64 dots (16 waves), serial
// top-'needed' pick, win_t bits. One barrier per count-round.
// ---------------------------------------------------------------------------
__global__ __launch_bounds__(1024) void k2_fused(const unsigned* __restrict__ KeyT,
                                                 const int* __restrict__ Cptr,
                                                 const float* __restrict__ A,
                                                 const float* __restrict__ W,
                                                 unsigned* __restrict__ khi_g,
                                                 unsigned long long* __restrict__ win_t) {
    const int e = blockIdx.x, tid = threadIdx.x;
    const int wid = tid >> 6, lane = tid & 63;
    const int C = *Cptr;
    const unsigned* col = KeyT + (size_t)e * BS;

    unsigned key[16];
#pragma unroll
    for (int j4 = 0; j4 < 4; ++j4) {
        const uint4 v = *(const uint4*)(col + j4 * 4096 + tid * 4);
        key[j4 * 4 + 0] = v.x; key[j4 * 4 + 1] = v.y;
        key[j4 * 4 + 2] = v.z; key[j4 * 4 + 3] = v.w;
    }
    // token index of key[j] = (j>>2)*4096 + tid*4 + (j&3)

    __shared__ int s_arr[20];   // one slot per count-round (max 2+17+1)
    __shared__ int s_nc;
    __shared__ int sidx[CAP];
    __shared__ double sval[CAP];
    if (tid < 20) s_arr[tid] = 0;
    if (tid == 0) s_nc = 0;
    __syncthreads();

    int step = 0;
    auto bcount = [&](unsigned T) -> int {  // count(key >= T) over all 16384
        int c = 0;
#pragma unroll
        for (int j = 0; j < 16; ++j) c += (key[j] >= T);
#pragma unroll
        for (int off = 32; off; off >>= 1) c += __shfl_xor(c, off);
        if (lane == 0) atomicAdd(&s_arr[step], c);
        __syncthreads();
        return s_arr[step++];
    };

    const int cLo = bcount(0xC0000000u);  // count(logit >= 2.0)
    const int cHi = bcount(0xC0800000u);  // count(logit >= 4.0)
    unsigned K; int bstart;
    if (cLo >= C && cHi < C) { K = 0xC0000000u; bstart = 22; }  // fast path
    else                     { K = 0u;          bstart = 31; }  // safe fallback
    for (int b = bstart; b >= 15; --b) {
        const unsigned T = K | (1u << b);
        if (bcount(T) >= C) K = T;
    }
    // C-th key in [K, K+0x8000): bracket the threshold, widen by DELTA.
    const float vlo = key2f(K);
    const float vhi = key2f(K + 0x8000u);
    const unsigned khi = f2key(vhi + DELTA);
    const unsigned klo = f2key(vlo - DELTA);
    const int nd = bcount(khi + 1u);  // definite ins: key > khi
    int need = C - nd;

#pragma unroll
    for (int j = 0; j < 16; ++j) {
        if (key[j] >= klo && key[j] <= khi) {
            const int pos = atomicAdd(&s_nc, 1);
            if (pos < CAP) sidx[pos] = (j >> 2) * 4096 + tid * 4 + (j & 3);
        }
    }
    __syncthreads();
    int n = s_nc; if (n > CAP) n = CAP;
    if (need > n) need = n; if (need < 0) need = 0;

    // exact fp64 dots for candidates, one wave each (16 waves)
    const float* Wr = W + (size_t)e * HDIM;
    for (int c = wid; c < n; c += 16) {
        const int t = sidx[c];
        const float* Ar = A + (size_t)t * HDIM;
        double ps = 0.0;
#pragma unroll 8
        for (int j = 0; j < HDIM / 64; ++j)
            ps += (double)Ar[j * 64 + lane] * (double)Wr[j * 64 + lane];
#pragma unroll
        for (int off = 32; off; off >>= 1) ps += __shfl_xor(ps, off);
        if (lane == 0) sval[c] = ps;
    }
    __syncthreads();
    if (tid == 0) {
        khi_g[e] = khi;
        for (int s = 0; s < need; ++s) {  // top-'need' by (fp64 desc, idx asc)
            int best = -1;
            for (int c = 0; c < n; ++c) {
                if (sidx[c] < 0) continue;
                if (best < 0 || sval[c] > sval[best] ||
                    (sval[c] == sval[best] && sidx[c] < sidx[best]))
                    best = c;
            }
            atomicOr(&win_t[sidx[best]], 1ull << e);
            sidx[best] = -1;
        }
    }
}

// ---------------------------------------------------------------------------
// K3: per-token softmax+mask+renorm (single reduction pass; |logit| small).
// map = (key > khi) | token-major winner bit. Per-block fp64 importance
// partials (no global atomics). REVERTED to round-0 form: the last-block
// threadfence fusion cost ~100 us (1024 device-scope fences = L2 writebacks).
// ---------------------------------------------------------------------------
__global__ __launch_bounds__(256) void k3_softmax(const float* __restrict__ Lg,
                                                  const unsigned* __restrict__ khi_g,
                                                  const unsigned long long* __restrict__ win_t,
                                                  float* __restrict__ probs,
                                                  float* __restrict__ out_map,
                                                  double* __restrict__ imp_partial) {
    const int tid = threadIdx.x, w = tid >> 6, e = tid & 63, b = blockIdx.x;
    __shared__ unsigned skhi[64];
    __shared__ double sim[4][64];
    if (tid < 64) skhi[tid] = khi_g[tid];
    __syncthreads();
    const unsigned kh = skhi[e];
    double accim = 0.0;
#pragma unroll
    for (int it = 0; it < 16; ++it) {
        const int t = b * 64 + it * 4 + w;
        const float x = Lg[(size_t)t * NE + e];
        const unsigned key = f2key(x);
        float mfl;
        if (key > kh) mfl = 1.f;
        else mfl = (float)((win_t[t] >> e) & 1ull);
        const float ev = expf(x);
        const float evm = ev * mfl;
        float s1 = ev, s2 = evm;
#pragma unroll
        for (int off = 32; off; off >>= 1) {
            s1 += __shfl_xor(s1, off);
            s2 += __shfl_xor(s2, off);
        }
        const float o = evm / (s2 + 1e-6f * s1);  // == (p*m)/(sum(p*m)+eps)
        probs[(size_t)t * NE + e] = o;
        out_map[(size_t)t * NE + e] = mfl;
        accim += (double)o;
    }
    sim[w][e] = accim;
    __syncthreads();
    if (w == 0)
        imp_partial[(size_t)b * NE + e] = sim[0][e] + sim[1][e] + sim[2][e] + sim[3][e];
}

// ---------------------------------------------------------------------------
// K4: reduce importance partials; aux = (std(imp,ddof=1)/(mean+eps))^2.
// load == C exactly per expert -> load_loss == 0.
// ---------------------------------------------------------------------------
__global__ __launch_bounds__(64) void k4_aux(const double* __restrict__ imp_partial,
                                             float* __restrict__ out_aux) {
    const int e = threadIdx.x;
    double v = 0.0;
    for (int b = 0; b < 256; ++b) v += imp_partial[(size_t)b * NE + e];
    double s = v;
#pragma unroll
    for (int off = 32; off; off >>= 1) s += __shfl_xor(s, off);
    const double mean = s / 64.0;
    const double d = v - mean;
    double ss = d * d;
#pragma unroll
    for (int off = 32; off; off >>= 1) ss += __shfl_xor(ss, off);
    if (e == 0) {
        const double var = ss / 63.0;
        const double dn = mean + 1e-6;
        out_aux[0] = (float)(var / (dn * dn));
    }
}

extern "C" void kernel_launch(void* const* d_in, const int* in_sizes, int n_in,
                              void* d_out, int out_size, void* d_ws, size_t ws_size,
                              hipStream_t stream) {
    const float* A = (const float*)d_in[0];
    const float* W = (const float*)d_in[1];
    const int* Cptr = (const int*)d_in[2];

    float* out_probs = (float*)d_out;
    float* out_map = out_probs + (size_t)BS * NE;
    float* out_aux = out_map + (size_t)BS * NE;

    char* wsb = (char*)d_ws;
    float*              Lg     = (float*)wsb;                                    // 4 MB
    unsigned*           KeyT   = (unsigned*)(wsb + (4ull << 20));                // 4 MB
    unsigned short*     Wh     = (unsigned short*)(wsb + (8ull << 20));          // 512 KB
    unsigned short*     Wl     = (unsigned short*)(wsb + (8ull << 20) + (512ull << 10));
    unsigned long long* win_t  = (unsigned long long*)(wsb + (9ull << 20));      // 128 KB
    unsigned*           khi_g  = (unsigned*)(wsb + (9ull << 20) + (128ull << 10));
    double*             imp_p  = (double*)(wsb + (9ull << 20) + (256ull << 10)); // 128 KB

    k0_init<<<256, 256, 0, stream>>>(W, Wh, Wl, win_t);
    k1_gemm<<<BS / TT, 256, 0, stream>>>(A, Wh, Wl, Lg, KeyT);
    k2_fused<<<NE, 1024, 0, stream>>>(KeyT, Cptr, A, W, khi_g, win_t);
    k3_softmax<<<BS / 64, 256, 0, stream>>>(Lg, khi_g, win_t, out_probs, out_map, imp_p);
    k4_aux<<<1, 64, 0, stream>>>(imp_p, out_aux);
}

// Round 3
// 449.767 us; speedup vs baseline: 1.2534x; 1.0428x over previous
//
#include <hip/hip_runtime.h>
#include <hip/hip_bf16.h>

#define BS 16384    // B*S tokens
#define HDIM 4096   // hidden dim
#define NE 64       // experts
#define KC 64       // K-chunk per LDS stage
#define TT 32       // tokens per block (K1)
#define CAP 512     // max boundary candidates per expert
#define DELTA 2e-3f // bf16-split GEMM error margin (actual err ~2e-5 rms)
#define K3B 512     // k3 grid: 32 tokens/block, 2 blocks/CU

typedef __bf16 bf16x8 __attribute__((ext_vector_type(8)));
typedef float f32x4 __attribute__((ext_vector_type(4)));
union Frag { uint4 q; bf16x8 v; };

__device__ inline unsigned f2key(float f) {
    unsigned u = __float_as_uint(f);
    return (u & 0x80000000u) ? ~u : (u | 0x80000000u);
}
__device__ inline float key2f(unsigned k) {
    unsigned u = (k & 0x80000000u) ? (k ^ 0x80000000u) : ~k;
    return __uint_as_float(u);
}
__device__ inline unsigned pack_hi(float a, float b) {  // bf16(a)|bf16(b)<<16 (trunc)
    return (__float_as_uint(a) >> 16) | (__float_as_uint(b) & 0xFFFF0000u);
}
__device__ inline float bf16_resid(float a) {  // a - trunc_bf16(a), exact
    return a - __uint_as_float(__float_as_uint(a) & 0xFFFF0000u);
}

// ---------------------------------------------------------------------------
// K1: logits = A @ W^T via bf16-split MFMA (AhBh+AlBh+AhBl, 16x16x32).
// 32 tok x 64 exp tile, 256 thr (4 waves), grid 512 -> 2 blocks/CU.
// NEW vs proven version: W is staged directly from fp32 and hi/lo-split
// in-stage (identical math to the old k0 conversion; same VMEM bytes since
// fp32 W == Wh+Wl bytes) -> k0 eliminated. win_t zeroed at block entry.
// Core MFMA loop, LDS layout, and epilogue are byte-identical.
// ---------------------------------------------------------------------------
__global__ __launch_bounds__(256, 2) void k1_gemm(const float* __restrict__ A,
                                                  const float* __restrict__ W,
                                                  float* __restrict__ Lg,
                                                  unsigned* __restrict__ KeyT,
                                                  unsigned long long* __restrict__ win_t) {
    // per buffer (13824 shorts): As_h[32][72] @0, As_l @2304, Ws_h[64][72] @4608,
    // Ws_l @9216. Two buffers = 27648 shorts = 55296 B.
    __shared__ __align__(16) unsigned short sbuf[2 * 13824];

    const int tid = threadIdx.x;
    const int T0 = blockIdx.x * TT;

    if (tid < TT) win_t[T0 + tid] = 0ull;  // replaces k0's win_t zeroing

    const int arow = tid >> 3, aseg = tid & 7;  // A staging: row 0..31, 8-float seg

    const int lane = tid & 63, w = tid >> 6;
    const int m = lane & 15, q = lane >> 4;
    const int wm = w & 1;   // M tile (16 tokens)
    const int wn = w >> 1;  // N half (32 experts)

    const float* Aprow = A + (size_t)(T0 + arow) * HDIM + aseg * 8;

    f32x4 acc[2] = {{0.f, 0.f, 0.f, 0.f}, {0.f, 0.f, 0.f, 0.f}};

    float4 pa0 = *(const float4*)(Aprow);
    float4 pa1 = *(const float4*)(Aprow + 4);
    float4 pwf[4];  // W fp32 prefetch: 64 rows x 64 floats per chunk, 16 floats/thread
#pragma unroll
    for (int i = 0; i < 4; ++i) {
        const int u = i * 256 + tid;               // 0..1023 float4 units
        const int r = u >> 4, seg = u & 15;        // row 0..63, float4 seg 0..15
        pwf[i] = *(const float4*)(W + (size_t)r * HDIM + seg * 4);
    }

    // stage chunk 0 into buffer 0
    {
        unsigned short* B = sbuf;
        uint4 H, L;
        H.x = pack_hi(pa0.x, pa0.y); H.y = pack_hi(pa0.z, pa0.w);
        H.z = pack_hi(pa1.x, pa1.y); H.w = pack_hi(pa1.z, pa1.w);
        L.x = pack_hi(bf16_resid(pa0.x), bf16_resid(pa0.y));
        L.y = pack_hi(bf16_resid(pa0.z), bf16_resid(pa0.w));
        L.z = pack_hi(bf16_resid(pa1.x), bf16_resid(pa1.y));
        L.w = pack_hi(bf16_resid(pa1.z), bf16_resid(pa1.w));
        *(uint4*)(B + arow * 72 + aseg * 8) = H;
        *(uint4*)(B + 2304 + arow * 72 + aseg * 8) = L;
#pragma unroll
        for (int i = 0; i < 4; ++i) {
            const int u = i * 256 + tid;
            const int r = u >> 4, seg = u & 15;
            const float4 wv = pwf[i];
            uint2 hh, ll;
            hh.x = pack_hi(wv.x, wv.y); hh.y = pack_hi(wv.z, wv.w);
            ll.x = pack_hi(bf16_resid(wv.x), bf16_resid(wv.y));
            ll.y = pack_hi(bf16_resid(wv.z), bf16_resid(wv.w));
            *(uint2*)(B + 4608 + r * 72 + seg * 4) = hh;
            *(uint2*)(B + 9216 + r * 72 + seg * 4) = ll;
        }
    }

    for (int c = 0; c < HDIM / KC; ++c) {
        if (c + 1 < HDIM / KC) {  // issue prefetch for chunk c+1
            const int c0 = (c + 1) * KC;
            pa0 = *(const float4*)(Aprow + c0);
            pa1 = *(const float4*)(Aprow + c0 + 4);
#pragma unroll
            for (int i = 0; i < 4; ++i) {
                const int u = i * 256 + tid;
                const int r = u >> 4, seg = u & 15;
                pwf[i] = *(const float4*)(W + (size_t)r * HDIM + c0 + seg * 4);
            }
        }
        __syncthreads();  // buf[c&1] visible; prior reads of buf[(c+1)&1] done
        {
            const unsigned short* B = sbuf + (c & 1) * 13824;
            const unsigned short* Ash = B + (wm * 16 + m) * 72;
            const unsigned short* Asl = Ash + 2304;
#pragma unroll
            for (int kh = 0; kh < 2; ++kh) {
                const int ko = kh * 32 + q * 8;
                Frag ah, al;
                ah.q = *(const uint4*)(Ash + ko);
                al.q = *(const uint4*)(Asl + ko);
#pragma unroll
                for (int nt = 0; nt < 2; ++nt) {
                    const int er = wn * 32 + nt * 16 + m;
                    Frag bh, bl;
                    bh.q = *(const uint4*)(B + 4608 + er * 72 + ko);
                    bl.q = *(const uint4*)(B + 9216 + er * 72 + ko);
                    acc[nt] = __builtin_amdgcn_mfma_f32_16x16x32_bf16(ah.v, bh.v, acc[nt], 0, 0, 0);
                    acc[nt] = __builtin_amdgcn_mfma_f32_16x16x32_bf16(al.v, bh.v, acc[nt], 0, 0, 0);
                    acc[nt] = __builtin_amdgcn_mfma_f32_16x16x32_bf16(ah.v, bl.v, acc[nt], 0, 0, 0);
                }
            }
        }
        if (c + 1 < HDIM / KC) {  // stage chunk c+1 into the other buffer
            unsigned short* B = sbuf + ((c + 1) & 1) * 13824;
            uint4 H, L;
            H.x = pack_hi(pa0.x, pa0.y); H.y = pack_hi(pa0.z, pa0.w);
            H.z = pack_hi(pa1.x, pa1.y); H.w = pack_hi(pa1.z, pa1.w);
            L.x = pack_hi(bf16_resid(pa0.x), bf16_resid(pa0.y));
            L.y = pack_hi(bf16_resid(pa0.z), bf16_resid(pa0.w));
            L.z = pack_hi(bf16_resid(pa1.x), bf16_resid(pa1.y));
            L.w = pack_hi(bf16_resid(pa1.z), bf16_resid(pa1.w));
            *(uint4*)(B + arow * 72 + aseg * 8) = H;
            *(uint4*)(B + 2304 + arow * 72 + aseg * 8) = L;
#pragma unroll
            for (int i = 0; i < 4; ++i) {
                const int u = i * 256 + tid;
                const int r = u >> 4, seg = u & 15;
                const float4 wv = pwf[i];
                uint2 hh, ll;
                hh.x = pack_hi(wv.x, wv.y); hh.y = pack_hi(wv.z, wv.w);
                ll.x = pack_hi(bf16_resid(wv.x), bf16_resid(wv.y));
                ll.y = pack_hi(bf16_resid(wv.z), bf16_resid(wv.w));
                *(uint2*)(B + 4608 + r * 72 + seg * 4) = hh;
                *(uint2*)(B + 9216 + r * 72 + seg * 4) = ll;
            }
        }
    }

    // Epilogue: Lg direct, KeyT via LDS transpose (coalesced per expert)
    __syncthreads();
    float* Sc = (float*)sbuf;  // [32][68] floats = 8704 B
#pragma unroll
    for (int nt = 0; nt < 2; ++nt) {
        const int e = wn * 32 + nt * 16 + m;  // C/D: col = lane&15
#pragma unroll
        for (int r = 0; r < 4; ++r) {
            const int tl = wm * 16 + q * 4 + r;  // C/D: row = quad*4+reg
            const float v = acc[nt][r];
            Sc[tl * 68 + e] = v;
            Lg[(size_t)(T0 + tl) * NE + e] = v;
        }
    }
    __syncthreads();
    {
        const int e = tid >> 2, jj = tid & 3;  // 8 tokens per thread
        unsigned kk[8];
#pragma unroll
        for (int r = 0; r < 8; ++r) kk[r] = f2key(Sc[(jj * 8 + r) * 68 + e]);
        uint4 v0 = {kk[0], kk[1], kk[2], kk[3]}, v1 = {kk[4], kk[5], kk[6], kk[7]};
        unsigned* dst = KeyT + (size_t)e * BS + T0 + jj * 8;
        *(uint4*)dst = v0;
        *(uint4*)(dst + 4) = v1;
    }
}

// ---------------------------------------------------------------------------
// K2 (fused select+resolve): per-expert C-th-largest key bracket via ONE-PASS
// 256-bin LDS histogram over key range [2.0, 4.0) (bin = 2^15 keys, exactly
// the old binary-search granularity -> identical K). Only ~6% of keys land
// in range -> ~1k LDS atomics/block. Wave-0 suffix-scan picks the bracket.
// Runtime-verified; exact binary-search fallback if threshold out of range.
// Candidates (~11 avg) resolved by exact fp64 dots (16 waves), serial
// top-'needed' pick, win_t bits.
// ---------------------------------------------------------------------------
__global__ __launch_bounds__(1024) void k2_fused(const unsigned* __restrict__ KeyT,
                                                 const int* __restrict__ Cptr,
                                                 const float* __restrict__ A,
                                                 const float* __restrict__ W,
                                                 unsigned* __restrict__ khi_g,
                                                 unsigned long long* __restrict__ win_t) {
    const int e = blockIdx.x, tid = threadIdx.x;
    const int wid = tid >> 6, lane = tid & 63;
    const int C = *Cptr;
    const unsigned* col = KeyT + (size_t)e * BS;

    unsigned key[16];
#pragma unroll
    for (int j4 = 0; j4 < 4; ++j4) {
        const uint4 v = *(const uint4*)(col + j4 * 4096 + tid * 4);
        key[j4 * 4 + 0] = v.x; key[j4 * 4 + 1] = v.y;
        key[j4 * 4 + 2] = v.z; key[j4 * 4 + 3] = v.w;
    }
    // token index of key[j] = (j>>2)*4096 + tid*4 + (j&3)

    __shared__ int hist[256];
    __shared__ int s_arr[20];   // slots for fallback bcount rounds
    __shared__ int s_top;       // count(key >= RT)
    __shared__ int s_bin;       // selected bin via atomicMax
    __shared__ int s_cnt;       // nd-count slot
    __shared__ int s_nc;
    __shared__ int sidx[CAP];
    __shared__ double sval[CAP];

    if (tid < 256) hist[tid] = 0;
    if (tid < 20) s_arr[tid] = 0;
    if (tid == 0) { s_top = 0; s_bin = -1; s_cnt = 0; s_nc = 0; }
    __syncthreads();

    const unsigned RB = 0xC0000000u;  // key(2.0)
    const unsigned RT = 0xC0800000u;  // key(4.0)
#pragma unroll
    for (int j = 0; j < 16; ++j) {
        if (key[j] >= RT) atomicAdd(&s_top, 1);
        else if (key[j] >= RB) atomicAdd(&hist[(key[j] - RB) >> 15], 1);
    }
    __syncthreads();

    // wave 0: suffix-scan hist, pick largest bin b with S(b) >= C - s_top
    if (wid == 0) {
        const int b0 = lane * 4;
        const int h0 = hist[b0], h1 = hist[b0 + 1], h2 = hist[b0 + 2], h3 = hist[b0 + 3];
        const int s = h0 + h1 + h2 + h3;
        int suf = s;  // becomes sum over lanes >= lane
#pragma unroll
        for (int off = 1; off < 64; off <<= 1) {
            const int v = __shfl_down(suf, off);
            if (lane + off < 64) suf += v;
        }
        const int tail = suf - s;  // sum over lanes > lane
        const int S3 = tail + h3, S2 = S3 + h2, S1 = S2 + h1, S0 = S1 + h0;
        const int Cp = C - s_top;
        int best = -1;
        if (Cp > 0) {
            if (S3 >= Cp) best = b0 + 3;
            else if (S2 >= Cp) best = b0 + 2;
            else if (S1 >= Cp) best = b0 + 1;
            else if (S0 >= Cp) best = b0;
        }
        if (best >= 0) atomicMax(&s_bin, best);
    }
    __syncthreads();

    unsigned K;
    if (s_top < C && s_bin >= 0) {
        K = RB + ((unsigned)s_bin << 15);  // identical to binary-search-to-bit-15 result
    } else {
        // exact fallback: full binary search bits 31..15 (uniform branch)
        int step = 0;
        K = 0u;
        for (int b = 31; b >= 15; --b) {
            const unsigned T = K | (1u << b);
            int c = 0;
#pragma unroll
            for (int j = 0; j < 16; ++j) c += (key[j] >= T);
#pragma unroll
            for (int off = 32; off; off >>= 1) c += __shfl_xor(c, off);
            if (lane == 0) atomicAdd(&s_arr[step], c);
            __syncthreads();
            if (s_arr[step++] >= C) K = T;
        }
    }

    // C-th key in [K, K+0x8000): bracket the threshold, widen by DELTA.
    const float vlo = key2f(K);
    const float vhi = key2f(K + 0x8000u);
    const unsigned khi = f2key(vhi + DELTA);
    const unsigned klo = f2key(vlo - DELTA);

    // nd = definite ins (key > khi), one count round
    {
        int c = 0;
#pragma unroll
        for (int j = 0; j < 16; ++j) c += (key[j] > khi);
#pragma unroll
        for (int off = 32; off; off >>= 1) c += __shfl_xor(c, off);
        if (lane == 0) atomicAdd(&s_cnt, c);
    }
#pragma unroll
    for (int j = 0; j < 16; ++j) {
        if (key[j] >= klo && key[j] <= khi) {
            const int pos = atomicAdd(&s_nc, 1);
            if (pos < CAP) sidx[pos] = (j >> 2) * 4096 + tid * 4 + (j & 3);
        }
    }
    __syncthreads();
    int need = C - s_cnt;
    int n = s_nc; if (n > CAP) n = CAP;
    if (need > n) need = n; if (need < 0) need = 0;

    // exact fp64 dots for candidates, one wave each (16 waves)
    const float* Wr = W + (size_t)e * HDIM;
    for (int c = wid; c < n; c += 16) {
        const int t = sidx[c];
        const float* Ar = A + (size_t)t * HDIM;
        double ps = 0.0;
#pragma unroll 8
        for (int j = 0; j < HDIM / 64; ++j)
            ps += (double)Ar[j * 64 + lane] * (double)Wr[j * 64 + lane];
#pragma unroll
        for (int off = 32; off; off >>= 1) ps += __shfl_xor(ps, off);
        if (lane == 0) sval[c] = ps;
    }
    __syncthreads();
    if (tid == 0) {
        khi_g[e] = khi;
        for (int s = 0; s < need; ++s) {  // top-'need' by (fp64 desc, idx asc)
            int best = -1;
            for (int c = 0; c < n; ++c) {
                if (sidx[c] < 0) continue;
                if (best < 0 || sval[c] > sval[best] ||
                    (sval[c] == sval[best] && sidx[c] < sidx[best]))
                    best = c;
            }
            atomicOr(&win_t[sidx[best]], 1ull << e);
            sidx[best] = -1;
        }
    }
}

// ---------------------------------------------------------------------------
// K3: per-token softmax+mask+renorm (single reduction pass; |logit| small).
// map = (key > khi) | token-major winner bit. Per-block fp64 importance
// partials (no global atomics, no fences). Grid 512 -> 2 waves/SIMD.
// ---------------------------------------------------------------------------
__global__ __launch_bounds__(256) void k3_softmax(const float* __restrict__ Lg,
                                                  const unsigned* __restrict__ khi_g,
                                                  const unsigned long long* __restrict__ win_t,
                                                  float* __restrict__ probs,
                                                  float* __restrict__ out_map,
                                                  double* __restrict__ imp_partial) {
    const int tid = threadIdx.x, w = tid >> 6, e = tid & 63, b = blockIdx.x;
    __shared__ unsigned skhi[64];
    __shared__ double sim[4][64];
    if (tid < 64) skhi[tid] = khi_g[tid];
    __syncthreads();
    const unsigned kh = skhi[e];
    double accim = 0.0;
#pragma unroll
    for (int it = 0; it < 8; ++it) {
        const int t = b * 32 + it * 4 + w;
        const float x = Lg[(size_t)t * NE + e];
        const unsigned key = f2key(x);
        float mfl;
        if (key > kh) mfl = 1.f;
        else mfl = (float)((win_t[t] >> e) & 1ull);
        const float ev = expf(x);
        const float evm = ev * mfl;
        float s1 = ev, s2 = evm;
#pragma unroll
        for (int off = 32; off; off >>= 1) {
            s1 += __shfl_xor(s1, off);
            s2 += __shfl_xor(s2, off);
        }
        const float o = evm / (s2 + 1e-6f * s1);  // == (p*m)/(sum(p*m)+eps)
        probs[(size_t)t * NE + e] = o;
        out_map[(size_t)t * NE + e] = mfl;
        accim += (double)o;
    }
    sim[w][e] = accim;
    __syncthreads();
    if (w == 0)
        imp_partial[(size_t)b * NE + e] = sim[0][e] + sim[1][e] + sim[2][e] + sim[3][e];
}

// ---------------------------------------------------------------------------
// K4: reduce importance partials; aux = (std(imp,ddof=1)/(mean+eps))^2.
// 512 threads (8 waves): 64 strided loads/thread instead of 256+ serial.
// load == C exactly per expert -> load_loss == 0.
// ---------------------------------------------------------------------------
__global__ __launch_bounds__(512) void k4_aux(const double* __restrict__ imp_partial,
                                              float* __restrict__ out_aux) {
    const int tid = threadIdx.x, w = tid >> 6, e = tid & 63;
    __shared__ double sp[8][64];
    double v = 0.0;
    for (int b = w; b < K3B; b += 8) v += imp_partial[(size_t)b * NE + e];
    sp[w][e] = v;
    __syncthreads();
    if (w == 0) {
        const double ve = sp[0][e] + sp[1][e] + sp[2][e] + sp[3][e] +
                          sp[4][e] + sp[5][e] + sp[6][e] + sp[7][e];
        double s = ve;
#pragma unroll
        for (int off = 32; off; off >>= 1) s += __shfl_xor(s, off);
        const double mean = s / 64.0;
        const double d = ve - mean;
        double ss = d * d;
#pragma unroll
        for (int off = 32; off; off >>= 1) ss += __shfl_xor(ss, off);
        if (e == 0) {
            const double var = ss / 63.0;
            const double dn = mean + 1e-6;
            out_aux[0] = (float)(var / (dn * dn));
        }
    }
}

extern "C" void kernel_launch(void* const* d_in, const int* in_sizes, int n_in,
                              void* d_out, int out_size, void* d_ws, size_t ws_size,
                              hipStream_t stream) {
    const float* A = (const float*)d_in[0];
    const float* W = (const float*)d_in[1];
    const int* Cptr = (const int*)d_in[2];

    float* out_probs = (float*)d_out;
    float* out_map = out_probs + (size_t)BS * NE;
    float* out_aux = out_map + (size_t)BS * NE;

    char* wsb = (char*)d_ws;
    float*              Lg     = (float*)wsb;                                    // 4 MB
    unsigned*           KeyT   = (unsigned*)(wsb + (4ull << 20));                // 4 MB
    unsigned long long* win_t  = (unsigned long long*)(wsb + (8ull << 20));      // 128 KB
    unsigned*           khi_g  = (unsigned*)(wsb + (8ull << 20) + (128ull << 10));
    double*             imp_p  = (double*)(wsb + (8ull << 20) + (256ull << 10)); // 256 KB

    k1_gemm<<<BS / TT, 256, 0, stream>>>(A, W, Lg, KeyT, win_t);
    k2_fused<<<NE, 1024, 0, stream>>>(KeyT, Cptr, A, W, khi_g, win_t);
    k3_softmax<<<K3B, 256, 0, stream>>>(Lg, khi_g, win_t, out_probs, out_map, imp_p);
    k4_aux<<<1, 512, 0, stream>>>(imp_p, out_aux);
}

// Round 4
// 448.442 us; speedup vs baseline: 1.2571x; 1.0030x over previous
//
#include <hip/hip_runtime.h>
#include <hip/hip_bf16.h>

#define BS 16384    // B*S tokens
#define HDIM 4096   // hidden dim
#define NE 64       // experts
#define KC 64       // K-chunk per LDS stage
#define TT 32       // tokens per block (K1)
#define CAP 512     // max boundary candidates per expert
#define DELTA 2e-3f // bf16-split GEMM error margin (actual err ~2e-5 rms)
#define K3B 512     // k3 grid: 32 tokens/block, 2 blocks/CU

typedef __bf16 bf16x8 __attribute__((ext_vector_type(8)));
typedef float f32x4 __attribute__((ext_vector_type(4)));
union Frag { uint4 q; bf16x8 v; };

__device__ inline unsigned f2key(float f) {
    unsigned u = __float_as_uint(f);
    return (u & 0x80000000u) ? ~u : (u | 0x80000000u);
}
__device__ inline float key2f(unsigned k) {
    unsigned u = (k & 0x80000000u) ? (k ^ 0x80000000u) : ~k;
    return __uint_as_float(u);
}
__device__ inline unsigned pack_hi(float a, float b) {  // bf16(a)|bf16(b)<<16 (trunc)
    return (__float_as_uint(a) >> 16) | (__float_as_uint(b) & 0xFFFF0000u);
}
__device__ inline float bf16_resid(float a) {  // a - trunc_bf16(a), exact
    return a - __uint_as_float(__float_as_uint(a) & 0xFFFF0000u);
}

// ---------------------------------------------------------------------------
// K1: logits = A @ W^T via bf16-split MFMA (AhBh+AlBh+AhBl, 16x16x32).
// 32 tok x 64 exp tile. NEW: 512 threads (8 waves, each owning one 16x16
// output tile: wm = w&1 M-tile, wn = w>>1 N-tile) -> 4 waves/SIMD at
// 2 blocks/CU for latency hiding; per-wave staging halved (1 A-float4 +
// 2 W-float4 per thread per chunk). LDS layout byte-identical to the
// proven 256-thread version; W hi/lo split in-stage (k0 eliminated).
// ---------------------------------------------------------------------------
__global__ __launch_bounds__(512, 4) void k1_gemm(const float* __restrict__ A,
                                                  const float* __restrict__ W,
                                                  float* __restrict__ Lg,
                                                  unsigned* __restrict__ KeyT,
                                                  unsigned long long* __restrict__ win_t) {
    // per buffer (13824 shorts): As_h[32][72] @0, As_l @2304, Ws_h[64][72] @4608,
    // Ws_l @9216. Two buffers = 27648 shorts = 55296 B.
    __shared__ __align__(16) unsigned short sbuf[2 * 13824];

    const int tid = threadIdx.x;
    const int T0 = blockIdx.x * TT;

    if (tid < TT) win_t[T0 + tid] = 0ull;  // replaces k0's win_t zeroing

    const int arow = tid >> 4, aseg = tid & 15;  // A staging: row 0..31, float4 seg 0..15

    const int lane = tid & 63, w = tid >> 6;     // 8 waves
    const int m = lane & 15, q = lane >> 4;
    const int wm = w & 1;   // M tile (16 tokens)
    const int wn = w >> 1;  // N tile (16 experts), 0..3

    const float* Aprow = A + (size_t)(T0 + arow) * HDIM + aseg * 4;

    f32x4 acc = {0.f, 0.f, 0.f, 0.f};

    float4 pa = *(const float4*)(Aprow);
    float4 pwf[2];  // W fp32 prefetch: 64 rows x 64 floats per chunk, 8 floats/thread
#pragma unroll
    for (int i = 0; i < 2; ++i) {
        const int u = i * 512 + tid;               // 0..1023 float4 units
        const int r = u >> 4, seg = u & 15;        // row 0..63, float4 seg 0..15
        pwf[i] = *(const float4*)(W + (size_t)r * HDIM + seg * 4);
    }

    // stage chunk 0 into buffer 0
    {
        unsigned short* B = sbuf;
        uint2 H, L;
        H.x = pack_hi(pa.x, pa.y); H.y = pack_hi(pa.z, pa.w);
        L.x = pack_hi(bf16_resid(pa.x), bf16_resid(pa.y));
        L.y = pack_hi(bf16_resid(pa.z), bf16_resid(pa.w));
        *(uint2*)(B + arow * 72 + aseg * 4) = H;
        *(uint2*)(B + 2304 + arow * 72 + aseg * 4) = L;
#pragma unroll
        for (int i = 0; i < 2; ++i) {
            const int u = i * 512 + tid;
            const int r = u >> 4, seg = u & 15;
            const float4 wv = pwf[i];
            uint2 hh, ll;
            hh.x = pack_hi(wv.x, wv.y); hh.y = pack_hi(wv.z, wv.w);
            ll.x = pack_hi(bf16_resid(wv.x), bf16_resid(wv.y));
            ll.y = pack_hi(bf16_resid(wv.z), bf16_resid(wv.w));
            *(uint2*)(B + 4608 + r * 72 + seg * 4) = hh;
            *(uint2*)(B + 9216 + r * 72 + seg * 4) = ll;
        }
    }

    for (int c = 0; c < HDIM / KC; ++c) {
        if (c + 1 < HDIM / KC) {  // issue prefetch for chunk c+1
            const int c0 = (c + 1) * KC;
            pa = *(const float4*)(Aprow + c0);
#pragma unroll
            for (int i = 0; i < 2; ++i) {
                const int u = i * 512 + tid;
                const int r = u >> 4, seg = u & 15;
                pwf[i] = *(const float4*)(W + (size_t)r * HDIM + c0 + seg * 4);
            }
        }
        __syncthreads();  // buf[c&1] visible; prior reads of buf[(c+1)&1] done
        {
            const unsigned short* B = sbuf + (c & 1) * 13824;
            const unsigned short* Ash = B + (wm * 16 + m) * 72;
            const unsigned short* Asl = Ash + 2304;
            const int er = wn * 16 + m;
            const unsigned short* Bh = B + 4608 + er * 72;
            const unsigned short* Bl = B + 9216 + er * 72;
#pragma unroll
            for (int kh = 0; kh < 2; ++kh) {
                const int ko = kh * 32 + q * 8;
                Frag ah, al, bh, bl;
                ah.q = *(const uint4*)(Ash + ko);
                al.q = *(const uint4*)(Asl + ko);
                bh.q = *(const uint4*)(Bh + ko);
                bl.q = *(const uint4*)(Bl + ko);
                acc = __builtin_amdgcn_mfma_f32_16x16x32_bf16(ah.v, bh.v, acc, 0, 0, 0);
                acc = __builtin_amdgcn_mfma_f32_16x16x32_bf16(al.v, bh.v, acc, 0, 0, 0);
                acc = __builtin_amdgcn_mfma_f32_16x16x32_bf16(ah.v, bl.v, acc, 0, 0, 0);
            }
        }
        if (c + 1 < HDIM / KC) {  // stage chunk c+1 into the other buffer
            unsigned short* B = sbuf + ((c + 1) & 1) * 13824;
            uint2 H, L;
            H.x = pack_hi(pa.x, pa.y); H.y = pack_hi(pa.z, pa.w);
            L.x = pack_hi(bf16_resid(pa.x), bf16_resid(pa.y));
            L.y = pack_hi(bf16_resid(pa.z), bf16_resid(pa.w));
            *(uint2*)(B + arow * 72 + aseg * 4) = H;
            *(uint2*)(B + 2304 + arow * 72 + aseg * 4) = L;
#pragma unroll
            for (int i = 0; i < 2; ++i) {
                const int u = i * 512 + tid;
                const int r = u >> 4, seg = u & 15;
                const float4 wv = pwf[i];
                uint2 hh, ll;
                hh.x = pack_hi(wv.x, wv.y); hh.y = pack_hi(wv.z, wv.w);
                ll.x = pack_hi(bf16_resid(wv.x), bf16_resid(wv.y));
                ll.y = pack_hi(bf16_resid(wv.z), bf16_resid(wv.w));
                *(uint2*)(B + 4608 + r * 72 + seg * 4) = hh;
                *(uint2*)(B + 9216 + r * 72 + seg * 4) = ll;
            }
        }
    }

    // Epilogue: Lg direct, KeyT via LDS transpose (coalesced per expert)
    __syncthreads();
    float* Sc = (float*)sbuf;  // [32][68] floats = 8704 B
    {
        const int e = wn * 16 + m;  // C/D: col = lane&15
#pragma unroll
        for (int r = 0; r < 4; ++r) {
            const int tl = wm * 16 + q * 4 + r;  // C/D: row = quad*4+reg
            const float v = acc[r];
            Sc[tl * 68 + e] = v;
            Lg[(size_t)(T0 + tl) * NE + e] = v;
        }
    }
    __syncthreads();
    {
        const int e = tid >> 3, jj = tid & 7;  // 4 tokens per thread
        unsigned kk[4];
#pragma unroll
        for (int r = 0; r < 4; ++r) kk[r] = f2key(Sc[(jj * 4 + r) * 68 + e]);
        uint4 v0 = {kk[0], kk[1], kk[2], kk[3]};
        *(uint4*)(KeyT + (size_t)e * BS + T0 + jj * 4) = v0;
    }
}

// ---------------------------------------------------------------------------
// K2 (fused select+resolve): per-expert C-th-largest key bracket via ONE-PASS
// 256-bin LDS histogram over key range [2.0, 4.0) (bin = 2^15 keys, exactly
// the old binary-search granularity -> identical K). Runtime-verified; exact
// binary-search fallback. Candidates (~11 avg) resolved by exact fp64 dots
// (16 waves), serial top-'needed' pick, win_t bits. (UNCHANGED.)
// ---------------------------------------------------------------------------
__global__ __launch_bounds__(1024) void k2_fused(const unsigned* __restrict__ KeyT,
                                                 const int* __restrict__ Cptr,
                                                 const float* __restrict__ A,
                                                 const float* __restrict__ W,
                                                 unsigned* __restrict__ khi_g,
                                                 unsigned long long* __restrict__ win_t) {
    const int e = blockIdx.x, tid = threadIdx.x;
    const int wid = tid >> 6, lane = tid & 63;
    const int C = *Cptr;
    const unsigned* col = KeyT + (size_t)e * BS;

    unsigned key[16];
#pragma unroll
    for (int j4 = 0; j4 < 4; ++j4) {
        const uint4 v = *(const uint4*)(col + j4 * 4096 + tid * 4);
        key[j4 * 4 + 0] = v.x; key[j4 * 4 + 1] = v.y;
        key[j4 * 4 + 2] = v.z; key[j4 * 4 + 3] = v.w;
    }
    // token index of key[j] = (j>>2)*4096 + tid*4 + (j&3)

    __shared__ int hist[256];
    __shared__ int s_arr[20];   // slots for fallback bcount rounds
    __shared__ int s_top;       // count(key >= RT)
    __shared__ int s_bin;       // selected bin via atomicMax
    __shared__ int s_cnt;       // nd-count slot
    __shared__ int s_nc;
    __shared__ int sidx[CAP];
    __shared__ double sval[CAP];

    if (tid < 256) hist[tid] = 0;
    if (tid < 20) s_arr[tid] = 0;
    if (tid == 0) { s_top = 0; s_bin = -1; s_cnt = 0; s_nc = 0; }
    __syncthreads();

    const unsigned RB = 0xC0000000u;  // key(2.0)
    const unsigned RT = 0xC0800000u;  // key(4.0)
#pragma unroll
    for (int j = 0; j < 16; ++j) {
        if (key[j] >= RT) atomicAdd(&s_top, 1);
        else if (key[j] >= RB) atomicAdd(&hist[(key[j] - RB) >> 15], 1);
    }
    __syncthreads();

    // wave 0: suffix-scan hist, pick largest bin b with S(b) >= C - s_top
    if (wid == 0) {
        const int b0 = lane * 4;
        const int h0 = hist[b0], h1 = hist[b0 + 1], h2 = hist[b0 + 2], h3 = hist[b0 + 3];
        const int s = h0 + h1 + h2 + h3;
        int suf = s;  // becomes sum over lanes >= lane
#pragma unroll
        for (int off = 1; off < 64; off <<= 1) {
            const int v = __shfl_down(suf, off);
            if (lane + off < 64) suf += v;
        }
        const int tail = suf - s;  // sum over lanes > lane
        const int S3 = tail + h3, S2 = S3 + h2, S1 = S2 + h1, S0 = S1 + h0;
        const int Cp = C - s_top;
        int best = -1;
        if (Cp > 0) {
            if (S3 >= Cp) best = b0 + 3;
            else if (S2 >= Cp) best = b0 + 2;
            else if (S1 >= Cp) best = b0 + 1;
            else if (S0 >= Cp) best = b0;
        }
        if (best >= 0) atomicMax(&s_bin, best);
    }
    __syncthreads();

    unsigned K;
    if (s_top < C && s_bin >= 0) {
        K = RB + ((unsigned)s_bin << 15);  // identical to binary-search-to-bit-15 result
    } else {
        // exact fallback: full binary search bits 31..15 (uniform branch)
        int step = 0;
        K = 0u;
        for (int b = 31; b >= 15; --b) {
            const unsigned T = K | (1u << b);
            int c = 0;
#pragma unroll
            for (int j = 0; j < 16; ++j) c += (key[j] >= T);
#pragma unroll
            for (int off = 32; off; off >>= 1) c += __shfl_xor(c, off);
            if (lane == 0) atomicAdd(&s_arr[step], c);
            __syncthreads();
            if (s_arr[step++] >= C) K = T;
        }
    }

    // C-th key in [K, K+0x8000): bracket the threshold, widen by DELTA.
    const float vlo = key2f(K);
    const float vhi = key2f(K + 0x8000u);
    const unsigned khi = f2key(vhi + DELTA);
    const unsigned klo = f2key(vlo - DELTA);

    // nd = definite ins (key > khi), one count round
    {
        int c = 0;
#pragma unroll
        for (int j = 0; j < 16; ++j) c += (key[j] > khi);
#pragma unroll
        for (int off = 32; off; off >>= 1) c += __shfl_xor(c, off);
        if (lane == 0) atomicAdd(&s_cnt, c);
    }
#pragma unroll
    for (int j = 0; j < 16; ++j) {
        if (key[j] >= klo && key[j] <= khi) {
            const int pos = atomicAdd(&s_nc, 1);
            if (pos < CAP) sidx[pos] = (j >> 2) * 4096 + tid * 4 + (j & 3);
        }
    }
    __syncthreads();
    int need = C - s_cnt;
    int n = s_nc; if (n > CAP) n = CAP;
    if (need > n) need = n; if (need < 0) need = 0;

    // exact fp64 dots for candidates, one wave each (16 waves)
    const float* Wr = W + (size_t)e * HDIM;
    for (int c = wid; c < n; c += 16) {
        const int t = sidx[c];
        const float* Ar = A + (size_t)t * HDIM;
        double ps = 0.0;
#pragma unroll 8
        for (int j = 0; j < HDIM / 64; ++j)
            ps += (double)Ar[j * 64 + lane] * (double)Wr[j * 64 + lane];
#pragma unroll
        for (int off = 32; off; off >>= 1) ps += __shfl_xor(ps, off);
        if (lane == 0) sval[c] = ps;
    }
    __syncthreads();
    if (tid == 0) {
        khi_g[e] = khi;
        for (int s = 0; s < need; ++s) {  // top-'need' by (fp64 desc, idx asc)
            int best = -1;
            for (int c = 0; c < n; ++c) {
                if (sidx[c] < 0) continue;
                if (best < 0 || sval[c] > sval[best] ||
                    (sval[c] == sval[best] && sidx[c] < sidx[best]))
                    best = c;
            }
            atomicOr(&win_t[sidx[best]], 1ull << e);
            sidx[best] = -1;
        }
    }
}

// ---------------------------------------------------------------------------
// K3: per-token softmax+mask+renorm (single reduction pass; |logit| small).
// map = (key > khi) | token-major winner bit. Per-block fp64 importance
// partials (no global atomics, no fences). Grid 512. (UNCHANGED.)
// ---------------------------------------------------------------------------
__global__ __launch_bounds__(256) void k3_softmax(const float* __restrict__ Lg,
                                                  const unsigned* __restrict__ khi_g,
                                                  const unsigned long long* __restrict__ win_t,
                                                  float* __restrict__ probs,
                                                  float* __restrict__ out_map,
                                                  double* __restrict__ imp_partial) {
    const int tid = threadIdx.x, w = tid >> 6, e = tid & 63, b = blockIdx.x;
    __shared__ unsigned skhi[64];
    __shared__ double sim[4][64];
    if (tid < 64) skhi[tid] = khi_g[tid];
    __syncthreads();
    const unsigned kh = skhi[e];
    double accim = 0.0;
#pragma unroll
    for (int it = 0; it < 8; ++it) {
        const int t = b * 32 + it * 4 + w;
        const float x = Lg[(size_t)t * NE + e];
        const unsigned key = f2key(x);
        float mfl;
        if (key > kh) mfl = 1.f;
        else mfl = (float)((win_t[t] >> e) & 1ull);
        const float ev = expf(x);
        const float evm = ev * mfl;
        float s1 = ev, s2 = evm;
#pragma unroll
        for (int off = 32; off; off >>= 1) {
            s1 += __shfl_xor(s1, off);
            s2 += __shfl_xor(s2, off);
        }
        const float o = evm / (s2 + 1e-6f * s1);  // == (p*m)/(sum(p*m)+eps)
        probs[(size_t)t * NE + e] = o;
        out_map[(size_t)t * NE + e] = mfl;
        accim += (double)o;
    }
    sim[w][e] = accim;
    __syncthreads();
    if (w == 0)
        imp_partial[(size_t)b * NE + e] = sim[0][e] + sim[1][e] + sim[2][e] + sim[3][e];
}

// ---------------------------------------------------------------------------
// K4: reduce importance partials; aux = (std(imp,ddof=1)/(mean+eps))^2.
// 512 threads (8 waves): 64 strided loads/thread. (UNCHANGED.)
// ---------------------------------------------------------------------------
__global__ __launch_bounds__(512) void k4_aux(const double* __restrict__ imp_partial,
                                              float* __restrict__ out_aux) {
    const int tid = threadIdx.x, w = tid >> 6, e = tid & 63;
    __shared__ double sp[8][64];
    double v = 0.0;
    for (int b = w; b < K3B; b += 8) v += imp_partial[(size_t)b * NE + e];
    sp[w][e] = v;
    __syncthreads();
    if (w == 0) {
        const double ve = sp[0][e] + sp[1][e] + sp[2][e] + sp[3][e] +
                          sp[4][e] + sp[5][e] + sp[6][e] + sp[7][e];
        double s = ve;
#pragma unroll
        for (int off = 32; off; off >>= 1) s += __shfl_xor(s, off);
        const double mean = s / 64.0;
        const double d = ve - mean;
        double ss = d * d;
#pragma unroll
        for (int off = 32; off; off >>= 1) ss += __shfl_xor(ss, off);
        if (e == 0) {
            const double var = ss / 63.0;
            const double dn = mean + 1e-6;
            out_aux[0] = (float)(var / (dn * dn));
        }
    }
}

extern "C" void kernel_launch(void* const* d_in, const int* in_sizes, int n_in,
                              void* d_out, int out_size, void* d_ws, size_t ws_size,
                              hipStream_t stream) {
    const float* A = (const float*)d_in[0];
    const float* W = (const float*)d_in[1];
    const int* Cptr = (const int*)d_in[2];

    float* out_probs = (float*)d_out;
    float* out_map = out_probs + (size_t)BS * NE;
    float* out_aux = out_map + (size_t)BS * NE;

    char* wsb = (char*)d_ws;
    float*              Lg     = (float*)wsb;                                    // 4 MB
    unsigned*           KeyT   = (unsigned*)(wsb + (4ull << 20));                // 4 MB
    unsigned long long* win_t  = (unsigned long long*)(wsb + (8ull << 20));      // 128 KB
    unsigned*           khi_g  = (unsigned*)(wsb + (8ull << 20) + (128ull << 10));
    double*             imp_p  = (double*)(wsb + (8ull << 20) + (256ull << 10)); // 256 KB

    k1_gemm<<<BS / TT, 512, 0, stream>>>(A, W, Lg, KeyT, win_t);
    k2_fused<<<NE, 1024, 0, stream>>>(KeyT, Cptr, A, W, khi_g, win_t);
    k3_softmax<<<K3B, 256, 0, stream>>>(Lg, khi_g, win_t, out_probs, out_map, imp_p);
    k4_aux<<<1, 512, 0, stream>>>(imp_p, out_aux);
}